// Round 5
// baseline (8393.350 us; speedup 1.0000x reference)
//
#include <hip/hip_runtime.h>
#include <stdint.h>

#define B_  32
#define T_  1024
#define I_  512
#define H_  1024
#define C_  512
#define G4H 4096
#define NWG 128

typedef __bf16 bf16x8 __attribute__((ext_vector_type(8)));
typedef float  f32x4  __attribute__((ext_vector_type(4)));
typedef unsigned long long u64;

#define POISON64 0xFFFFFFFFFFFFFFFFULL
#define POLL(x, p) while ((x) == POISON64) { __builtin_amdgcn_s_sleep(2); \
    (x) = __hip_atomic_load((p), __ATOMIC_RELAXED, __HIP_MEMORY_SCOPE_AGENT); }

__device__ __forceinline__ unsigned short f2bf(float f) {
    uint32_t b = __float_as_uint(f);
    b = (b + 0x7FFFu + ((b >> 16) & 1u)) >> 16;
    return (unsigned short)b;
}
__device__ __forceinline__ float sigf(float x)   { return 1.0f / (1.0f + __expf(-x)); }
__device__ __forceinline__ float tanh_f(float x) { return 2.0f / (1.0f + __expf(-2.0f * x)) - 1.0f; }

// ---------------- fp32 -> bf16 conversion (vectorized x4) ----------------
__global__ void cvt_kernel(const float* __restrict__ src, unsigned short* __restrict__ dst, int n4) {
    int i = blockIdx.x * blockDim.x + threadIdx.x;
    if (i < n4) {
        float4 v = ((const float4*)src)[i];
        ushort4 o;
        o.x = f2bf(v.x); o.y = f2bf(v.y); o.z = f2bf(v.z); o.w = f2bf(v.w);
        ((ushort4*)dst)[i] = o;
    }
}

// x: [B][T][I] fp32 -> [T][B][I] bf16
__global__ void cvt_x_kernel(const float* __restrict__ src, unsigned short* __restrict__ dst) {
    int i4 = blockIdx.x * blockDim.x + threadIdx.x;
    int b   = i4 / (T_ * I_ / 4);
    int rem = i4 % (T_ * I_ / 4);
    int t   = rem / (I_ / 4);
    int c4  = rem % (I_ / 4);
    float4 v = ((const float4*)src)[i4];
    ushort4 o;
    o.x = f2bf(v.x); o.y = f2bf(v.y); o.z = f2bf(v.z); o.w = f2bf(v.w);
    ((ushort4*)dst)[(t * B_ + b) * (I_ / 4) + c4] = o;
}

__global__ void bias_kernel(const float* __restrict__ a, const float* __restrict__ b, float* __restrict__ o) {
    int i = blockIdx.x * blockDim.x + threadIdx.x;
    if (i < G4H) o[i] = a[i] + b[i];
}

// fill via agent-scope stores: leaves NO L2 copies anywhere (unlike memset blit),
// so later plain loads can never hit a stale poison line.
__global__ void fill_kernel(u64* __restrict__ dst, u64 val, size_t n) {
    size_t i = (size_t)blockIdx.x * blockDim.x + threadIdx.x;
    size_t stride = (size_t)gridDim.x * blockDim.x;
    for (; i < n; i += stride)
        __hip_atomic_store(dst + i, val, __ATOMIC_RELAXED, __HIP_MEMORY_SCOPE_AGENT);
}

// ---------------- persistent LSTM recurrence, poison-pull dataflow ----------------
// 128 WGs x 512 threads (cooperative launch for co-residency; no grid.sync).
// WG wg owns hidden units [wg*8, wg*8+8) -> 32 gate cols.
// LDS: W_hh slice [32 cols][1024 K] bf16 XOR-swizzled (granule g ^ (col&7)) 64KB;
//      scratch[2 parity][8 waves][32 b][32 c] f32 64KB; hstage 512B.
// W_ih slice read from global (L2-resident 32KB/WG), x-phase overlaps h wait.
// h exchange: hall slots 1.. pre-poisoned 0xFFFF (unreachable for |h|<1 bf16);
// producers publish 8B agent-scope atomic stores; consumers agent-load u64
// granules and retry-if-poison -> detect IS the load (one LLC round trip).
// One __syncthreads per step; scratch parity makes WAR provably safe via the
// own-WG barrier alone.
__global__ __launch_bounds__(512, 1) void lstm_rec(
        const unsigned short* __restrict__ whh,   // [4096][1024] bf16
        const unsigned short* __restrict__ wih,   // [4096][512]  bf16
        const unsigned short* __restrict__ xb,    // [1024][32][512] bf16
        const float* __restrict__ bias,           // [4096] (b_ih + b_hh)
        unsigned short* __restrict__ hall)        // [1025][32][1024] bf16
{
    extern __shared__ char smem[];
    unsigned short* Wlds    = (unsigned short*)smem;                 // 65536 B
    float*          scratch = (float*)(smem + 65536);                // 65536 B
    unsigned short* hstage  = (unsigned short*)(smem + 131072);      // 512 B

    const int tid  = threadIdx.x;
    const int wg   = blockIdx.x;
    const int lane = tid & 63;
    const int wq   = tid >> 6;
    const int l15  = lane & 15;
    const int l4   = lane >> 4;

    // ---- one-time: stage W_hh slice into LDS (swizzled) ----
    for (int s = tid; s < 32 * 128; s += 512) {
        int col = s >> 7, g = s & 127;
        int grow = (col >> 3) * H_ + wg * 8 + (col & 7);
        int4 v = *(const int4*)(whh + (size_t)grow * H_ + g * 8);
        int gd = g ^ (col & 7);
        *(int4*)(Wlds + col * 1024 + gd * 8) = v;
    }
    // per-thread bias registers (pointwise threads only)
    float bs0 = 0.f, bs1 = 0.f, bs2 = 0.f, bs3 = 0.f;
    if (tid < 256) {
        int u = tid & 7;
        bs0 = bias[0 * H_ + wg * 8 + u];
        bs1 = bias[1 * H_ + wg * 8 + u];
        bs2 = bias[2 * H_ + wg * 8 + u];
        bs3 = bias[3 * H_ + wg * 8 + u];
    }
    __syncthreads();

    float c_state = 0.0f;

    for (int t = 0; t < T_; ++t) {
        f32x4 acc[2][2];
        #pragma unroll
        for (int a = 0; a < 2; a++)
            #pragma unroll
            for (int b = 0; b < 2; b++) acc[a][b] = (f32x4){0.f, 0.f, 0.f, 0.f};

        // ---- x-part (no h dependency; W_ih from global/L2) ----
        #pragma unroll
        for (int kxs = 0; kxs < 2; kxs++) {
            int kk = wq * 64 + kxs * 32 + l4 * 8;
            bf16x8 af[2];
            #pragma unroll
            for (int mt = 0; mt < 2; mt++) {
                int bb = mt * 16 + l15;
                af[mt] = *(const bf16x8*)(xb + ((size_t)t * B_ + bb) * I_ + kk);
            }
            bf16x8 bfr[2];
            #pragma unroll
            for (int nt = 0; nt < 2; nt++) {
                int col = nt * 16 + l15;
                int grow = (col >> 3) * H_ + wg * 8 + (col & 7);
                bfr[nt] = *(const bf16x8*)(wih + (size_t)grow * I_ + kk);
            }
            #pragma unroll
            for (int mt = 0; mt < 2; mt++)
                #pragma unroll
                for (int nt = 0; nt < 2; nt++)
                    acc[mt][nt] = __builtin_amdgcn_mfma_f32_16x16x32_bf16(af[mt], bfr[nt], acc[mt][nt], 0, 0, 0);
        }

        // ---- h-part: issue all agent-scope granule loads, then poll+MFMA ----
        const unsigned short* hprev = hall + (size_t)t * (B_ * H_);
        u64 hv[4][4];
        #pragma unroll
        for (int khs = 0; khs < 4; khs++) {
            int kk = wq * 128 + khs * 32 + l4 * 8;
            const u64* p0 = (const u64*)(hprev + l15 * H_ + kk);
            const u64* p1 = (const u64*)(hprev + (16 + l15) * H_ + kk);
            hv[khs][0] = __hip_atomic_load(p0,     __ATOMIC_RELAXED, __HIP_MEMORY_SCOPE_AGENT);
            hv[khs][1] = __hip_atomic_load(p0 + 1, __ATOMIC_RELAXED, __HIP_MEMORY_SCOPE_AGENT);
            hv[khs][2] = __hip_atomic_load(p1,     __ATOMIC_RELAXED, __HIP_MEMORY_SCOPE_AGENT);
            hv[khs][3] = __hip_atomic_load(p1 + 1, __ATOMIC_RELAXED, __HIP_MEMORY_SCOPE_AGENT);
        }
        #pragma unroll
        for (int khs = 0; khs < 4; khs++) {
            int kk = wq * 128 + khs * 32 + l4 * 8;
            const u64* p0 = (const u64*)(hprev + l15 * H_ + kk);
            const u64* p1 = (const u64*)(hprev + (16 + l15) * H_ + kk);
            POLL(hv[khs][0], p0); POLL(hv[khs][1], p0 + 1);
            POLL(hv[khs][2], p1); POLL(hv[khs][3], p1 + 1);
            union { u64 q[2]; bf16x8 v; } ua, ub;
            ua.q[0] = hv[khs][0]; ua.q[1] = hv[khs][1];
            ub.q[0] = hv[khs][2]; ub.q[1] = hv[khs][3];
            int g = wq * 16 + khs * 4 + l4;
            bf16x8 bfr[2];
            #pragma unroll
            for (int nt = 0; nt < 2; nt++) {
                int col = nt * 16 + l15;
                int gg = g ^ (col & 7);
                bfr[nt] = *(const bf16x8*)(Wlds + col * 1024 + gg * 8);
            }
            acc[0][0] = __builtin_amdgcn_mfma_f32_16x16x32_bf16(ua.v, bfr[0], acc[0][0], 0, 0, 0);
            acc[0][1] = __builtin_amdgcn_mfma_f32_16x16x32_bf16(ua.v, bfr[1], acc[0][1], 0, 0, 0);
            acc[1][0] = __builtin_amdgcn_mfma_f32_16x16x32_bf16(ub.v, bfr[0], acc[1][0], 0, 0, 0);
            acc[1][1] = __builtin_amdgcn_mfma_f32_16x16x32_bf16(ub.v, bfr[1], acc[1][1], 0, 0, 0);
        }

        // ---- partials -> per-wave parity scratch (swizzled plain writes, 2-way max) ----
        float* myscr = scratch + (t & 1) * 8192 + wq * 1024;
        #pragma unroll
        for (int mt = 0; mt < 2; mt++)
            #pragma unroll
            for (int nt = 0; nt < 2; nt++)
                #pragma unroll
                for (int r = 0; r < 4; r++) {
                    int bb  = mt * 16 + l4 * 4 + r;
                    int col = nt * 16 + l15;
                    myscr[bb * 32 + (col ^ ((bb & 7) << 2))] = acc[mt][nt][r];
                }
        __syncthreads();   // the ONLY barrier per step

        // ---- pointwise + publish (waves 0-3); waves 4-7 run ahead ----
        if (tid < 256) {
            int bb = tid >> 3, u = tid & 7;
            int sw = (bb & 7) << 2;
            float p0 = bs0, p1 = bs1, p2 = bs2, p3 = bs3;
            const float* base = scratch + (t & 1) * 8192 + bb * 32;
            #pragma unroll
            for (int q = 0; q < 8; q++) {
                const float* sc = base + q * 1024;
                p0 += sc[(u)      ^ sw];
                p1 += sc[(8 + u)  ^ sw];
                p2 += sc[(16 + u) ^ sw];
                p3 += sc[(24 + u) ^ sw];
            }
            float ig = sigf(p0), fg = sigf(p1), gg = tanh_f(p2), og = sigf(p3);
            c_state = fg * c_state + ig * gg;
            float h = og * tanh_f(c_state);
            hstage[bb * 8 + u] = f2bf(h);            // wave-private 128B chunk
            asm volatile("s_waitcnt lgkmcnt(0)" ::: "memory");

            int w = tid >> 6, i = tid & 63;
            if (i < 16) {
                int pb = w * 8 + (i >> 1), part = i & 1;
                u64 q = *(const u64*)(hstage + pb * 8 + part * 4);
                u64* dst = (u64*)(hall + ((size_t)(t + 1) * B_ + pb) * H_ + wg * 8 + part * 4);
                __hip_atomic_store(dst, q, __ATOMIC_RELAXED, __HIP_MEMORY_SCOPE_AGENT);
            }
            // no vmcnt drain, no flag: stores fly; consumers detect arrival by value
        }
    }
}

// ---------------- output GEMMs: C[M x N] = A[M x 1024] * B[N x 1024]^T + bias ----------------
template<int PERM>
__global__ __launch_bounds__(256) void gemm_bt(
        const unsigned short* __restrict__ A,
        const unsigned short* __restrict__ Bw,
        const float* __restrict__ bias,
        float* __restrict__ out)
{
    __shared__ unsigned short As[128 * 64];
    __shared__ unsigned short Bs[128 * 64];
    const int tid  = threadIdx.x;
    const int lane = tid & 63, w = tid >> 6;
    const int wm = w >> 1, wn = w & 1;
    const int mbase = blockIdx.y * 128, nbase = blockIdx.x * 128;
    const int l15 = lane & 15, l4 = lane >> 4;

    f32x4 acc[4][4];
    #pragma unroll
    for (int i = 0; i < 4; i++)
        #pragma unroll
        for (int j = 0; j < 4; j++) acc[i][j] = (f32x4){0.f, 0.f, 0.f, 0.f};

    for (int kb = 0; kb < 16; kb++) {
        __syncthreads();
        #pragma unroll
        for (int i = 0; i < 4; i++) {
            int s = i * 256 + tid;
            int row = s >> 3, g = s & 7;
            int gd = g ^ (row & 7);
            int4 va = *(const int4*)(A  + (mbase + row) * 1024 + kb * 64 + g * 8);
            *(int4*)(As + row * 64 + gd * 8) = va;
            int4 vb = *(const int4*)(Bw + (nbase + row) * 1024 + kb * 64 + g * 8);
            *(int4*)(Bs + row * 64 + gd * 8) = vb;
        }
        __syncthreads();
        #pragma unroll
        for (int kk = 0; kk < 2; kk++) {
            bf16x8 af[4], bf[4];
            #pragma unroll
            for (int mt = 0; mt < 4; mt++) {
                int row = wm * 64 + mt * 16 + l15;
                int gg = (kk * 4 + l4) ^ (row & 7);
                af[mt] = *(const bf16x8*)(As + row * 64 + gg * 8);
            }
            #pragma unroll
            for (int nt = 0; nt < 4; nt++) {
                int row = wn * 64 + nt * 16 + l15;
                int gg = (kk * 4 + l4) ^ (row & 7);
                bf[nt] = *(const bf16x8*)(Bs + row * 64 + gg * 8);
            }
            #pragma unroll
            for (int mt = 0; mt < 4; mt++)
                #pragma unroll
                for (int nt = 0; nt < 4; nt++)
                    acc[mt][nt] = __builtin_amdgcn_mfma_f32_16x16x32_bf16(af[mt], bf[nt], acc[mt][nt], 0, 0, 0);
        }
    }
    #pragma unroll
    for (int mt = 0; mt < 4; mt++)
        #pragma unroll
        for (int nt = 0; nt < 4; nt++)
            #pragma unroll
            for (int r = 0; r < 4; r++) {
                int grow = mbase + wm * 64 + mt * 16 + l4 * 4 + r;
                int gcol = nbase + wn * 64 + nt * 16 + l15;
                float v = acc[mt][nt][r] + bias[gcol];
                int idx;
                if (PERM == 1) {
                    int tt = grow >> 5, bb = grow & 31;
                    idx = (bb * 1024 + tt) * 512 + gcol;
                } else {
                    idx = grow * 1024 + gcol;
                }
                out[idx] = v;
            }
}

// ---------------- host ----------------
extern "C" void kernel_launch(void* const* d_in, const int* in_sizes, int n_in,
                              void* d_out, int out_size, void* d_ws, size_t ws_size,
                              hipStream_t stream) {
    (void)in_sizes; (void)n_in; (void)out_size; (void)ws_size;
    const float* x    = (const float*)d_in[0];
    const float* Wih  = (const float*)d_in[1];
    const float* Whh  = (const float*)d_in[2];
    const float* bih  = (const float*)d_in[3];
    const float* bhh  = (const float*)d_in[4];
    const float* fcw  = (const float*)d_in[5];
    const float* fcb  = (const float*)d_in[6];
    const float* lnw  = (const float*)d_in[7];
    const float* lnb  = (const float*)d_in[8];
    float* out = (float*)d_out;

    char* ws = (char*)d_ws;
    size_t o = 0;
    unsigned short* whh_b = (unsigned short*)(ws + o); o += 8388608;   // [4096][1024]
    unsigned short* wih_b = (unsigned short*)(ws + o); o += 4194304;   // [4096][512]
    unsigned short* fcw_b = (unsigned short*)(ws + o); o += 1048576;   // [512][1024]
    unsigned short* lnw_b = (unsigned short*)(ws + o); o += 2097152;   // [1024][1024]
    unsigned short* x_b   = (unsigned short*)(ws + o); o += 33554432;  // [1024][32][512]
    float*          bias_c = (float*)(ws + o);         o += 16384;     // [4096]
    unsigned short* hall  = (unsigned short*)(ws + o); o += 67174400;  // [1025][32][1024]

    // slot 0 = zeros; slots 1..1024 = poison, both via agent-scope fills (no L2 residue)
    fill_kernel<<<32, 256, 0, stream>>>((u64*)hall, 0ULL, 8192);
    fill_kernel<<<4096, 256, 0, stream>>>((u64*)(hall + 32768), POISON64, 8388608);

    cvt_kernel<<<4096,  256, 0, stream>>>(Whh, whh_b, 4194304 / 4);
    cvt_kernel<<<2048,  256, 0, stream>>>(Wih, wih_b, 2097152 / 4);
    cvt_kernel<<<512,   256, 0, stream>>>(fcw, fcw_b, 524288 / 4);
    cvt_kernel<<<1024,  256, 0, stream>>>(lnw, lnw_b, 1048576 / 4);
    cvt_x_kernel<<<16384, 256, 0, stream>>>(x, x_b);
    bias_kernel<<<16, 256, 0, stream>>>(bih, bhh, bias_c);

    const unsigned short* a0 = whh_b;
    const unsigned short* a1 = wih_b;
    const unsigned short* a2 = x_b;
    const float*          a3 = bias_c;
    unsigned short*       a4 = hall;
    void* args[5] = { (void*)&a0, (void*)&a1, (void*)&a2, (void*)&a3, (void*)&a4 };
    hipLaunchCooperativeKernel((void*)lstm_rec, dim3(NWG), dim3(512), args,
                               (unsigned)(65536 + 65536 + 512), stream);

    const unsigned short* hseq = hall + 32768;  // slot 1 = h at t=0
    gemm_bt<1><<<dim3(4, 256), 256, 0, stream>>>(hseq, fcw_b, fcb, out);
    gemm_bt<2><<<dim3(8, 256), 256, 0, stream>>>(hseq, lnw_b, lnb, out + 16777216);
}

// Round 6
// 7680.051 us; speedup vs baseline: 1.0929x; 1.0929x over previous
//
#include <hip/hip_runtime.h>
#include <stdint.h>

#define B_  32
#define T_  1024
#define I_  512
#define H_  1024
#define C_  512
#define G4H 4096
#define NWG 128

typedef __bf16 bf16x8 __attribute__((ext_vector_type(8)));
typedef float  f32x4  __attribute__((ext_vector_type(4)));
typedef unsigned long long u64;

__device__ __forceinline__ unsigned short f2bf(float f) {
    uint32_t b = __float_as_uint(f);
    b = (b + 0x7FFFu + ((b >> 16) & 1u)) >> 16;
    return (unsigned short)b;
}
__device__ __forceinline__ float bf2f(unsigned short v) {
    return __uint_as_float(((uint32_t)v) << 16);
}
__device__ __forceinline__ float sigf(float x)   { return 1.0f / (1.0f + __expf(-x)); }
__device__ __forceinline__ float tanh_f(float x) { return 2.0f / (1.0f + __expf(-2.0f * x)) - 1.0f; }

// ---------------- fp32 -> bf16 conversion (vectorized x4) ----------------
__global__ void cvt_kernel(const float* __restrict__ src, unsigned short* __restrict__ dst, int n4) {
    int i = blockIdx.x * blockDim.x + threadIdx.x;
    if (i < n4) {
        float4 v = ((const float4*)src)[i];
        ushort4 o;
        o.x = f2bf(v.x); o.y = f2bf(v.y); o.z = f2bf(v.z); o.w = f2bf(v.w);
        ((ushort4*)dst)[i] = o;
    }
}

// x: [B][T][I] fp32 -> [T][B][I] bf16 (fallback path only)
__global__ void cvt_x_kernel(const float* __restrict__ src, unsigned short* __restrict__ dst) {
    int i4 = blockIdx.x * blockDim.x + threadIdx.x;
    int b   = i4 / (T_ * I_ / 4);
    int rem = i4 % (T_ * I_ / 4);
    int t   = rem / (I_ / 4);
    int c4  = rem % (I_ / 4);
    float4 v = ((const float4*)src)[i4];
    ushort4 o;
    o.x = f2bf(v.x); o.y = f2bf(v.y); o.z = f2bf(v.z); o.w = f2bf(v.w);
    ((ushort4*)dst)[(t * B_ + b) * (I_ / 4) + c4] = o;
}

__global__ void bias_kernel(const float* __restrict__ a, const float* __restrict__ b, float* __restrict__ o) {
    int i = blockIdx.x * blockDim.x + threadIdx.x;
    if (i < G4H) o[i] = a[i] + b[i];
}

__global__ void fill_kernel(u64* __restrict__ dst, u64 val, size_t n) {
    size_t i = (size_t)blockIdx.x * blockDim.x + threadIdx.x;
    if (i < n)
        __hip_atomic_store(dst + i, val, __ATOMIC_RELAXED, __HIP_MEMORY_SCOPE_AGENT);
}

// ---------------- x_gates GEMM: xg[t][b][4096] = x[b][t][:] @ W_ih^T ----------------
// A [32768 rows = b*1024+t][512] bf16, Bw [4096][512] bf16, out bf16 [T][B][4096].
__global__ __launch_bounds__(256) void xg_gemm(
        const unsigned short* __restrict__ A,
        const unsigned short* __restrict__ Bw,
        unsigned short* __restrict__ out)
{
    __shared__ unsigned short As[128 * 64];
    __shared__ unsigned short Bs[128 * 64];
    const int tid  = threadIdx.x;
    const int lane = tid & 63, w = tid >> 6;
    const int wm = w >> 1, wn = w & 1;
    const int mbase = blockIdx.y * 128, nbase = blockIdx.x * 128;
    const int l15 = lane & 15, l4 = lane >> 4;

    f32x4 acc[4][4];
    #pragma unroll
    for (int i = 0; i < 4; i++)
        #pragma unroll
        for (int j = 0; j < 4; j++) acc[i][j] = (f32x4){0.f, 0.f, 0.f, 0.f};

    for (int kb = 0; kb < 8; kb++) {
        __syncthreads();
        #pragma unroll
        for (int i = 0; i < 4; i++) {
            int s = i * 256 + tid;
            int row = s >> 3, g = s & 7;
            int gd = g ^ (row & 7);
            int4 va = *(const int4*)(A  + (size_t)(mbase + row) * 512 + kb * 64 + g * 8);
            *(int4*)(As + row * 64 + gd * 8) = va;
            int4 vb = *(const int4*)(Bw + (size_t)(nbase + row) * 512 + kb * 64 + g * 8);
            *(int4*)(Bs + row * 64 + gd * 8) = vb;
        }
        __syncthreads();
        #pragma unroll
        for (int kk = 0; kk < 2; kk++) {
            bf16x8 af[4], bf[4];
            #pragma unroll
            for (int mt = 0; mt < 4; mt++) {
                int row = wm * 64 + mt * 16 + l15;
                int gg = (kk * 4 + l4) ^ (row & 7);
                af[mt] = *(const bf16x8*)(As + row * 64 + gg * 8);
            }
            #pragma unroll
            for (int nt = 0; nt < 4; nt++) {
                int row = wn * 64 + nt * 16 + l15;
                int gg = (kk * 4 + l4) ^ (row & 7);
                bf[nt] = *(const bf16x8*)(Bs + row * 64 + gg * 8);
            }
            #pragma unroll
            for (int mt = 0; mt < 4; mt++)
                #pragma unroll
                for (int nt = 0; nt < 4; nt++)
                    acc[mt][nt] = __builtin_amdgcn_mfma_f32_16x16x32_bf16(af[mt], bf[nt], acc[mt][nt], 0, 0, 0);
        }
    }
    #pragma unroll
    for (int mt = 0; mt < 4; mt++)
        #pragma unroll
        for (int nt = 0; nt < 4; nt++)
            #pragma unroll
            for (int r = 0; r < 4; r++) {
                int grow = mbase + wm * 64 + mt * 16 + l4 * 4 + r;
                int gcol = nbase + wn * 64 + nt * 16 + l15;
                int b = grow >> 10, t = grow & 1023;
                out[((size_t)t * B_ + b) * G4H + gcol] = f2bf(acc[mt][nt][r]);
            }
}

// ---------------- persistent LSTM recurrence ----------------
// 128 WGs x 512 threads. WG wg owns hidden units [wg*8, wg*8+8) -> 32 gate cols.
// LDS: W_hh [32 cols][1024 K] bf16 XOR-swizzled 64KB; scratch [8][32][32] f32 32KB
// (bank-swizzled, single buffer - WAR safe: scratch(t+1) writes are flag-gated
// behind own-WG pointwise reads of scratch(t)); hstage 512B; (+W_ih 32KB if !XG).
// Per step: [poll flags(t) by wave 7 only, 64 lanes x 4 u64 agent loads + sleep]
// -> bar_A -> (XG: prefetch xg regs) -> h-loads (plain cached) + 4 kstep MFMA
// (+x-part MFMA if !XG) -> scratch -> bar_B -> waves 0-3: pointwise, per-wave
// publish (hstage -> lgkmcnt -> 16x8B agent stores by lanes<16 -> vmcnt ->
// per-wave flag). Detection overlaps publish.
template<int XG>
__global__ __launch_bounds__(512, 1) void lstm_rec(
        const unsigned short* __restrict__ whh,   // [4096][1024] bf16
        const unsigned short* __restrict__ wih,   // [4096][512]  bf16 (!XG)
        const unsigned short* __restrict__ xb,    // [1024][32][512] bf16 (!XG)
        const unsigned short* __restrict__ xg,    // [1024][32][4096] bf16 (XG)
        const float* __restrict__ bias,           // [4096] (b_ih + b_hh)
        unsigned short* __restrict__ hall,        // [1025][32][1024] bf16 (slot 0 zeroed)
        unsigned int* __restrict__ flags)         // [1025][128][4] (pre-zeroed)
{
    extern __shared__ char smem[];
    unsigned short* Wlds    = (unsigned short*)smem;                 // 65536 B
    float*          scratch = (float*)(smem + 65536);                // 32768 B
    unsigned short* hstage  = (unsigned short*)(smem + 98304);       // 512 B
    unsigned short* Wih_l   = (unsigned short*)(smem + 98816);       // 32768 B if !XG

    const int tid  = threadIdx.x;
    const int wg   = blockIdx.x;
    const int lane = tid & 63;
    const int wq   = tid >> 6;
    const int l15  = lane & 15;
    const int l4   = lane >> 4;

    // ---- one-time: stage W_hh slice into LDS (swizzled) ----
    for (int s = tid; s < 32 * 128; s += 512) {
        int col = s >> 7, g = s & 127;
        int grow = (col >> 3) * H_ + wg * 8 + (col & 7);
        int4 v = *(const int4*)(whh + (size_t)grow * H_ + g * 8);
        int gd = g ^ (col & 7);
        *(int4*)(Wlds + col * 1024 + gd * 8) = v;
    }
    if (!XG) {
        for (int s = tid; s < 32 * 64; s += 512) {
            int col = s >> 6, g = s & 63;
            int grow = (col >> 3) * H_ + wg * 8 + (col & 7);
            int4 v = *(const int4*)(wih + (size_t)grow * I_ + g * 8);
            int gd = g ^ (col & 7);
            *(int4*)(Wih_l + col * 512 + gd * 8) = v;
        }
    }
    float bs0 = 0.f, bs1 = 0.f, bs2 = 0.f, bs3 = 0.f;
    if (tid < 256) {
        int u = tid & 7;
        bs0 = bias[0 * H_ + wg * 8 + u];
        bs1 = bias[1 * H_ + wg * 8 + u];
        bs2 = bias[2 * H_ + wg * 8 + u];
        bs3 = bias[3 * H_ + wg * 8 + u];
    }
    __syncthreads();

    float c_state = 0.0f;

    for (int t = 0; t < T_; ++t) {
        // ---- poller wave: wait for all 512 per-wave flags of slot t ----
        if (t > 0 && wq == 7) {
            const u64* fb = (const u64*)flags + (size_t)t * 256;
            #pragma unroll
            for (int j = 0; j < 4; j++) {
                const u64* p = fb + j * 64 + lane;
                u64 v = __hip_atomic_load(p, __ATOMIC_RELAXED, __HIP_MEMORY_SCOPE_AGENT);
                while (v != 0x0000000100000001ULL) {
                    __builtin_amdgcn_s_sleep(1);
                    v = __hip_atomic_load(p, __ATOMIC_RELAXED, __HIP_MEMORY_SCOPE_AGENT);
                }
            }
        }
        __syncthreads();   // bar_A: h slot t fully published

        // ---- prefetch x_gates for pointwise (hidden under h-phase) ----
        float xg0 = 0.f, xg1 = 0.f, xg2 = 0.f, xg3 = 0.f;
        if (XG && tid < 256) {
            int bb = tid >> 3, u = tid & 7;
            const unsigned short* xp = xg + ((size_t)t * B_ + bb) * G4H + wg * 8 + u;
            xg0 = bf2f(xp[0]);
            xg1 = bf2f(xp[1024]);
            xg2 = bf2f(xp[2048]);
            xg3 = bf2f(xp[3072]);
        }

        f32x4 acc[2][2];
        #pragma unroll
        for (int a = 0; a < 2; a++)
            #pragma unroll
            for (int b = 0; b < 2; b++) acc[a][b] = (f32x4){0.f, 0.f, 0.f, 0.f};

        if (!XG) {
            // ---- in-loop x-part (fallback) ----
            #pragma unroll
            for (int kxs = 0; kxs < 2; kxs++) {
                int kk = wq * 64 + kxs * 32 + l4 * 8;
                bf16x8 af[2];
                #pragma unroll
                for (int mt = 0; mt < 2; mt++) {
                    int bb = mt * 16 + l15;
                    af[mt] = *(const bf16x8*)(xb + ((size_t)t * B_ + bb) * I_ + kk);
                }
                int gb = kk >> 3;
                bf16x8 bfr[2];
                #pragma unroll
                for (int nt = 0; nt < 2; nt++) {
                    int col = nt * 16 + l15;
                    int gg = gb ^ (col & 7);
                    bfr[nt] = *(const bf16x8*)(Wih_l + col * 512 + gg * 8);
                }
                #pragma unroll
                for (int mt = 0; mt < 2; mt++)
                    #pragma unroll
                    for (int nt = 0; nt < 2; nt++)
                        acc[mt][nt] = __builtin_amdgcn_mfma_f32_16x16x32_bf16(af[mt], bfr[nt], acc[mt][nt], 0, 0, 0);
            }
        }

        // ---- h-part (plain cached loads; safe: first touch per launch is post-flag) ----
        const unsigned short* hprev = hall + (size_t)t * (B_ * H_);
        #pragma unroll
        for (int khs = 0; khs < 4; khs++) {
            int kk = wq * 128 + khs * 32 + l4 * 8;
            bf16x8 af[2];
            #pragma unroll
            for (int mt = 0; mt < 2; mt++) {
                int bb = mt * 16 + l15;
                af[mt] = *(const bf16x8*)(hprev + bb * H_ + kk);
            }
            int gb = kk >> 3;
            bf16x8 bfr[2];
            #pragma unroll
            for (int nt = 0; nt < 2; nt++) {
                int col = nt * 16 + l15;
                int gg = gb ^ (col & 7);
                bfr[nt] = *(const bf16x8*)(Wlds + col * 1024 + gg * 8);
            }
            #pragma unroll
            for (int mt = 0; mt < 2; mt++)
                #pragma unroll
                for (int nt = 0; nt < 2; nt++)
                    acc[mt][nt] = __builtin_amdgcn_mfma_f32_16x16x32_bf16(af[mt], bfr[nt], acc[mt][nt], 0, 0, 0);
        }

        // ---- partials -> per-wave scratch region (swizzled plain writes) ----
        float* myscr = scratch + wq * 1024;
        #pragma unroll
        for (int mt = 0; mt < 2; mt++)
            #pragma unroll
            for (int nt = 0; nt < 2; nt++)
                #pragma unroll
                for (int r = 0; r < 4; r++) {
                    int bb  = mt * 16 + l4 * 4 + r;
                    int col = nt * 16 + l15;
                    myscr[bb * 32 + (col ^ ((bb & 7) << 2))] = acc[mt][nt][r];
                }
        __syncthreads();   // bar_B: scratch(t) complete

        // ---- pointwise + per-wave publish (waves 0-3) ----
        if (tid < 256) {
            int bb = tid >> 3, u = tid & 7;
            int sw = (bb & 7) << 2;
            float p0 = bs0 + xg0, p1 = bs1 + xg1, p2 = bs2 + xg2, p3 = bs3 + xg3;
            const float* base = scratch + bb * 32;
            #pragma unroll
            for (int q = 0; q < 8; q++) {
                const float* sc = base + q * 1024;
                p0 += sc[(u)      ^ sw];
                p1 += sc[(8 + u)  ^ sw];
                p2 += sc[(16 + u) ^ sw];
                p3 += sc[(24 + u) ^ sw];
            }
            float ig = sigf(p0), fg = sigf(p1), gg = tanh_f(p2), og = sigf(p3);
            c_state = fg * c_state + ig * gg;
            float h = og * tanh_f(c_state);
            hstage[bb * 8 + u] = f2bf(h);            // wave-private 128B chunk
            asm volatile("s_waitcnt lgkmcnt(0)" ::: "memory");

            int w = wq, i = lane;
            if (i < 16) {
                int pb = w * 8 + (i >> 1), part = i & 1;
                u64 q = *(const u64*)(hstage + pb * 8 + part * 4);
                u64* dst = (u64*)(hall + ((size_t)(t + 1) * B_ + pb) * H_ + wg * 8 + part * 4);
                __hip_atomic_store(dst, q, __ATOMIC_RELAXED, __HIP_MEMORY_SCOPE_AGENT);
            }
            asm volatile("s_waitcnt vmcnt(0)" ::: "memory");
            if (i == 0)
                __hip_atomic_store(flags + (size_t)(t + 1) * 512 + wg * 4 + w, 1u,
                                   __ATOMIC_RELAXED, __HIP_MEMORY_SCOPE_AGENT);
        }
    }
}

// ---------------- output GEMMs: C[M x N] = A[M x 1024] * B[N x 1024]^T + bias ----------------
template<int PERM>
__global__ __launch_bounds__(256) void gemm_bt(
        const unsigned short* __restrict__ A,
        const unsigned short* __restrict__ Bw,
        const float* __restrict__ bias,
        float* __restrict__ out)
{
    __shared__ unsigned short As[128 * 64];
    __shared__ unsigned short Bs[128 * 64];
    const int tid  = threadIdx.x;
    const int lane = tid & 63, w = tid >> 6;
    const int wm = w >> 1, wn = w & 1;
    const int mbase = blockIdx.y * 128, nbase = blockIdx.x * 128;
    const int l15 = lane & 15, l4 = lane >> 4;

    f32x4 acc[4][4];
    #pragma unroll
    for (int i = 0; i < 4; i++)
        #pragma unroll
        for (int j = 0; j < 4; j++) acc[i][j] = (f32x4){0.f, 0.f, 0.f, 0.f};

    for (int kb = 0; kb < 16; kb++) {
        __syncthreads();
        #pragma unroll
        for (int i = 0; i < 4; i++) {
            int s = i * 256 + tid;
            int row = s >> 3, g = s & 7;
            int gd = g ^ (row & 7);
            int4 va = *(const int4*)(A  + (size_t)(mbase + row) * 1024 + kb * 64 + g * 8);
            *(int4*)(As + row * 64 + gd * 8) = va;
            int4 vb = *(const int4*)(Bw + (size_t)(nbase + row) * 1024 + kb * 64 + g * 8);
            *(int4*)(Bs + row * 64 + gd * 8) = vb;
        }
        __syncthreads();
        #pragma unroll
        for (int kk = 0; kk < 2; kk++) {
            bf16x8 af[4], bf[4];
            #pragma unroll
            for (int mt = 0; mt < 4; mt++) {
                int row = wm * 64 + mt * 16 + l15;
                int gg = (kk * 4 + l4) ^ (row & 7);
                af[mt] = *(const bf16x8*)(As + row * 64 + gg * 8);
            }
            #pragma unroll
            for (int nt = 0; nt < 4; nt++) {
                int row = wn * 64 + nt * 16 + l15;
                int gg = (kk * 4 + l4) ^ (row & 7);
                bf[nt] = *(const bf16x8*)(Bs + row * 64 + gg * 8);
            }
            #pragma unroll
            for (int mt = 0; mt < 4; mt++)
                #pragma unroll
                for (int nt = 0; nt < 4; nt++)
                    acc[mt][nt] = __builtin_amdgcn_mfma_f32_16x16x32_bf16(af[mt], bf[nt], acc[mt][nt], 0, 0, 0);
        }
    }
    #pragma unroll
    for (int mt = 0; mt < 4; mt++)
        #pragma unroll
        for (int nt = 0; nt < 4; nt++)
            #pragma unroll
            for (int r = 0; r < 4; r++) {
                int grow = mbase + wm * 64 + mt * 16 + l4 * 4 + r;
                int gcol = nbase + wn * 64 + nt * 16 + l15;
                float v = acc[mt][nt][r] + bias[gcol];
                int idx;
                if (PERM == 1) {
                    int tt = grow >> 5, bb = grow & 31;
                    idx = (bb * 1024 + tt) * 512 + gcol;
                } else {
                    idx = grow * 1024 + gcol;
                }
                out[idx] = v;
            }
}

// ---------------- host ----------------
extern "C" void kernel_launch(void* const* d_in, const int* in_sizes, int n_in,
                              void* d_out, int out_size, void* d_ws, size_t ws_size,
                              hipStream_t stream) {
    (void)in_sizes; (void)n_in; (void)out_size;
    const float* x    = (const float*)d_in[0];
    const float* Wih  = (const float*)d_in[1];
    const float* Whh  = (const float*)d_in[2];
    const float* bih  = (const float*)d_in[3];
    const float* bhh  = (const float*)d_in[4];
    const float* fcw  = (const float*)d_in[5];
    const float* fcb  = (const float*)d_in[6];
    const float* lnw  = (const float*)d_in[7];
    const float* lnb  = (const float*)d_in[8];
    float* out = (float*)d_out;

    char* ws = (char*)d_ws;
    size_t o = 0;
    unsigned short* whh_b = (unsigned short*)(ws + o); o += 8388608;   // [4096][1024]
    unsigned short* wih_b = (unsigned short*)(ws + o); o += 4194304;   // [4096][512]
    unsigned short* fcw_b = (unsigned short*)(ws + o); o += 1048576;   // [512][1024]
    unsigned short* lnw_b = (unsigned short*)(ws + o); o += 2097152;   // [1024][1024]
    unsigned short* x_b   = (unsigned short*)(ws + o); o += 33554432;  // 16.7M bf16
    float*          bias_c = (float*)(ws + o);         o += 16384;     // [4096]
    unsigned short* hall  = (unsigned short*)(ws + o); o += 67174400;  // [1025][32][1024]
    unsigned int*   flags = (unsigned int*)(ws + o);   o += 2099200;   // [1025][128][4]
    unsigned short* xgbuf = (unsigned short*)(ws + o);                 // [1024][32][4096] bf16
    const int use_xg = (ws_size >= o + 268435456) ? 1 : 0;

    hipMemsetAsync(flags, 0, 2099200, stream);
    fill_kernel<<<32, 256, 0, stream>>>((u64*)hall, 0ULL, 8192);   // h slot 0 = zeros

    cvt_kernel<<<4096,  256, 0, stream>>>(Whh, whh_b, 4194304 / 4);
    cvt_kernel<<<2048,  256, 0, stream>>>(Wih, wih_b, 2097152 / 4);
    cvt_kernel<<<512,   256, 0, stream>>>(fcw, fcw_b, 524288 / 4);
    cvt_kernel<<<1024,  256, 0, stream>>>(lnw, lnw_b, 1048576 / 4);
    bias_kernel<<<16, 256, 0, stream>>>(bih, bhh, bias_c);

    if (use_xg) {
        cvt_kernel<<<16384, 256, 0, stream>>>(x, x_b, 16777216 / 4);   // [B][T][I] bf16
        xg_gemm<<<dim3(32, 256), 256, 0, stream>>>(x_b, wih_b, xgbuf);
    } else {
        cvt_x_kernel<<<16384, 256, 0, stream>>>(x, x_b);               // [T][B][I] bf16
    }

    const unsigned short* a0 = whh_b;
    const unsigned short* a1 = wih_b;
    const unsigned short* a2 = x_b;
    const unsigned short* a3 = xgbuf;
    const float*          a4 = bias_c;
    unsigned short*       a5 = hall;
    unsigned int*         a6 = flags;
    void* args[7] = { (void*)&a0, (void*)&a1, (void*)&a2, (void*)&a3, (void*)&a4, (void*)&a5, (void*)&a6 };
    if (use_xg) {
        hipLaunchCooperativeKernel((void*)lstm_rec<1>, dim3(NWG), dim3(512), args,
                                   (unsigned)98816, stream);
    } else {
        hipLaunchCooperativeKernel((void*)lstm_rec<0>, dim3(NWG), dim3(512), args,
                                   (unsigned)131584, stream);
    }

    const unsigned short* hseq = hall + 32768;  // slot 1 = h at t=0
    gemm_bt<1><<<dim3(4, 256), 256, 0, stream>>>(hseq, fcw_b, fcb, out);
    gemm_bt<2><<<dim3(8, 256), 256, 0, stream>>>(hseq, lnw_b, lnb, out + 16777216);
}